// Round 6
// baseline (505.745 us; speedup 1.0000x reference)
//
#include <hip/hip_runtime.h>
#include <hip/hip_bf16.h>

#define T_LEN 256
#define B_DIM 128
#define EMB 1024
#define HID 1024
#define NLAB 50
#define M_ROWS (T_LEN * B_DIM)   // 32768
#define N3H 3072
#define KT 16                    // 1024 / BK=64

typedef __attribute__((ext_vector_type(8))) short short8;
typedef __attribute__((ext_vector_type(4))) float f32x4;

// ---- helpers ----
static __device__ __forceinline__ ushort f2b(float x) {
    unsigned u = __builtin_bit_cast(unsigned, x);
    unsigned lsb = (u >> 16) & 1u;
    u += 0x7fffu + lsb;
    return (ushort)(u >> 16);
}
static __device__ __forceinline__ float b2f(ushort u) {
    unsigned v = ((unsigned)u) << 16;
    return __builtin_bit_cast(float, v);
}
static __device__ __forceinline__ void gload16(const ushort* g, ushort* l) {
    __builtin_amdgcn_global_load_lds(
        (const __attribute__((address_space(1))) unsigned int*)g,
        (__attribute__((address_space(3))) unsigned int*)l,
        16, 0, 0);
}
static __device__ __forceinline__ float fast_sigmoid(float y) {
    return 1.f / (1.f + __expf(-y));
}
static __device__ __forceinline__ float fast_tanh(float y) {
    float e = __expf(2.f * y);
    return (e - 1.f) / (e + 1.f);
}

// ---- kernel 1: x = bf16(emb[sentence]), 16 rows per block ----
__global__ __launch_bounds__(256) void gather_convert(
    const int* __restrict__ sent, const float* __restrict__ emb,
    ushort* __restrict__ xb)
{
    const int row = blockIdx.x * 16 + (threadIdx.x >> 4);
    const int seg = threadIdx.x & 15;
    const size_t src = (size_t)sent[row] * EMB;
    const float4* ep = (const float4*)(emb + src);
    ushort4* op = (ushort4*)(xb + (size_t)row * EMB);
#pragma unroll
    for (int j = 0; j < 16; j++) {
        float4 v = ep[seg + j * 16];
        ushort4 o;
        o.x = f2b(v.x); o.y = f2b(v.y); o.z = f2b(v.z); o.w = f2b(v.w);
        op[seg + j * 16] = o;
    }
}

// ---- kernel 2: Wt[n][k] = bf16(W[k][n]) ----
__global__ __launch_bounds__(256) void transposeW(
    const float* __restrict__ W, ushort* __restrict__ Wt)
{
    __shared__ float tile[32][33];
    const int n0 = blockIdx.x * 32, k0 = blockIdx.y * 32;
    const int tx = threadIdx.x, ty = threadIdx.y;   // 32 x 8
#pragma unroll
    for (int j = 0; j < 32; j += 8)
        tile[ty + j][tx] = W[(size_t)(k0 + ty + j) * N3H + n0 + tx];
    __syncthreads();
#pragma unroll
    for (int j = 0; j < 32; j += 8)
        Wt[(size_t)(n0 + ty + j) * EMB + k0 + tx] = f2b(tile[tx][ty + j]);
}

// ---- kernel 3: 256x256 tile, BK=64, 8 waves, minimal 2-phase (m248 recipe) ----
// LDS per buffer: A chunked [kg][row] (kg 0..7 of 8 bf16, row 0..255), B same.
// Chunk c = kg*256+row at 16B offset c*16; linear dest for global_load_lds.
// Fragment read: 16-lane group reads 16 consecutive rows -> 256B contiguous,
// conflict-free (0 conflicts measured in R4 with this family).
__global__ __launch_bounds__(512, 1) void gemm256(
    const ushort* __restrict__ A, const ushort* __restrict__ Bt,
    const float* __restrict__ bias,
    ushort* __restrict__ zb, ushort* __restrict__ fb, ushort* __restrict__ ob)
{
    __shared__ ushort LDS[2 * 32768];   // 2 bufs x (A 32KB + B 32KB) = 128 KB

    const int tid = threadIdx.x;
    const int lane = tid & 63;
    const int w = tid >> 6;
    const int wr = w >> 2, wc = w & 3;          // 2 x 4 wave grid, wave-tile 128x64
    const int l15 = lane & 15, lh = lane >> 4;

    const int wg = blockIdx.x;
    const ushort *Ab, *Bb;
    const float* bptr;
    ushort* dst;
    int rowbase, colbase, Mvalid, maxrow;
    bool use_tanh;
    if (wg < 1024) {
        const int w2 = (wg & 7) * 128 + (wg >> 3);   // XCD-chunked, nt-fastest
        const int mt = w2 >> 3, nt = w2 & 7;
        Ab = A + (size_t)mt * 256 * EMB;
        Bb = Bt + (size_t)nt * 256 * EMB;
        bptr = bias + nt * 256;
        rowbase = mt * 256; Mvalid = 256; maxrow = 255;
        if (nt < 4) { dst = zb; colbase = nt * 256; use_tanh = true; }
        else        { dst = fb; colbase = nt * 256 - 1024; use_tanh = false; }
    } else {
        const int q = wg - 1024;
        Ab = A + (size_t)(M_ROWS - 128) * EMB;
        Bb = Bt + (size_t)(2048 + q * 256) * EMB;
        bptr = bias + 2048 + q * 256;
        rowbase = 0; colbase = q * 256; Mvalid = 128; maxrow = 127;
        dst = ob; use_tanh = false;
    }

    // stage-side: 4 A-chunks + 4 B-chunks per thread per K-step
    const ushort* gA[4];
    const ushort* gB[4];
    int dOf[4];
#pragma unroll
    for (int q = 0; q < 4; q++) {
        const int c = q * 512 + tid;
        const int kg = c >> 8, row = c & 255;
        gA[q] = Ab + (size_t)min(row, maxrow) * EMB + kg * 8;
        gB[q] = Bb + (size_t)row * EMB + kg * 8;
        dOf[q] = c * 8;
    }

#define STAGE(bp_, kt_) do {                                  \
        ushort* la_ = &LDS[(bp_) * 32768];                    \
        ushort* lb_ = la_ + 16384;                            \
        const int ko_ = (kt_) * 64;                           \
        gload16(gA[0] + ko_, la_ + dOf[0]);                   \
        gload16(gA[1] + ko_, la_ + dOf[1]);                   \
        gload16(gA[2] + ko_, la_ + dOf[2]);                   \
        gload16(gA[3] + ko_, la_ + dOf[3]);                   \
        gload16(gB[0] + ko_, lb_ + dOf[0]);                   \
        gload16(gB[1] + ko_, lb_ + dOf[1]);                   \
        gload16(gB[2] + ko_, lb_ + dOf[2]);                   \
        gload16(gB[3] + ko_, lb_ + dOf[3]);                   \
    } while (0)

    // read-side offsets for ks=0 (ushort units); ks=1 adds 4*256*8 = 8192
    int adA[8], adB[4];
#pragma unroll
    for (int mi = 0; mi < 8; mi++)
        adA[mi] = (lh * 256 + wr * 128 + mi * 16 + l15) * 8;
#pragma unroll
    for (int ni = 0; ni < 4; ni++)
        adB[ni] = (lh * 256 + wc * 64 + ni * 16 + l15) * 8;

    f32x4 acc[8][4] = {};

    STAGE(0, 0);
    asm volatile("s_waitcnt vmcnt(0)" ::: "memory");
    __builtin_amdgcn_s_barrier();

#define MQ(AI, ar)                                                                   \
    acc[AI][0] = __builtin_amdgcn_mfma_f32_16x16x32_bf16(ar, b0, acc[AI][0], 0,0,0); \
    acc[AI][1] = __builtin_amdgcn_mfma_f32_16x16x32_bf16(ar, b1, acc[AI][1], 0,0,0); \
    acc[AI][2] = __builtin_amdgcn_mfma_f32_16x16x32_bf16(ar, b2, acc[AI][2], 0,0,0); \
    acc[AI][3] = __builtin_amdgcn_mfma_f32_16x16x32_bf16(ar, b3, acc[AI][3], 0,0,0);

#pragma unroll 2
    for (int t = 0; t < KT; ++t) {
        const int buf = t & 1;
        if (t + 1 < KT) STAGE(buf ^ 1, t + 1);   // issue next tile first

        const ushort* Ablk = &LDS[buf * 32768];
        const ushort* Bblk = Ablk + 16384;

        // ---- ks = 0 ----
        {
            short8 a0 = *(const short8*)&Ablk[adA[0]];
            short8 a1 = *(const short8*)&Ablk[adA[1]];
            short8 a2 = *(const short8*)&Ablk[adA[2]];
            short8 a3 = *(const short8*)&Ablk[adA[3]];
            short8 a4 = *(const short8*)&Ablk[adA[4]];
            short8 a5 = *(const short8*)&Ablk[adA[5]];
            short8 a6 = *(const short8*)&Ablk[adA[6]];
            short8 a7 = *(const short8*)&Ablk[adA[7]];
            short8 b0 = *(const short8*)&Bblk[adB[0]];
            short8 b1 = *(const short8*)&Bblk[adB[1]];
            short8 b2 = *(const short8*)&Bblk[adB[2]];
            short8 b3 = *(const short8*)&Bblk[adB[3]];
            asm volatile("s_waitcnt lgkmcnt(0)" ::: "memory");
            __builtin_amdgcn_s_setprio(1);
            MQ(0, a0) MQ(1, a1) MQ(2, a2) MQ(3, a3)
            MQ(4, a4) MQ(5, a5) MQ(6, a6) MQ(7, a7)
            __builtin_amdgcn_s_setprio(0);
        }
        // ---- ks = 1 ----
        {
            short8 a0 = *(const short8*)&Ablk[adA[0] + 8192];
            short8 a1 = *(const short8*)&Ablk[adA[1] + 8192];
            short8 a2 = *(const short8*)&Ablk[adA[2] + 8192];
            short8 a3 = *(const short8*)&Ablk[adA[3] + 8192];
            short8 a4 = *(const short8*)&Ablk[adA[4] + 8192];
            short8 a5 = *(const short8*)&Ablk[adA[5] + 8192];
            short8 a6 = *(const short8*)&Ablk[adA[6] + 8192];
            short8 a7 = *(const short8*)&Ablk[adA[7] + 8192];
            short8 b0 = *(const short8*)&Bblk[adB[0] + 8192];
            short8 b1 = *(const short8*)&Bblk[adB[1] + 8192];
            short8 b2 = *(const short8*)&Bblk[adB[2] + 8192];
            short8 b3 = *(const short8*)&Bblk[adB[3] + 8192];
            asm volatile("s_waitcnt lgkmcnt(0)" ::: "memory");
            __builtin_amdgcn_s_setprio(1);
            MQ(0, a0) MQ(1, a1) MQ(2, a2) MQ(3, a3)
            MQ(4, a4) MQ(5, a5) MQ(6, a6) MQ(7, a7)
            __builtin_amdgcn_s_setprio(0);
        }

        if (t + 1 < KT) {
            asm volatile("s_waitcnt vmcnt(0)" ::: "memory");
            __builtin_amdgcn_s_barrier();
        }
    }
#undef MQ
#undef STAGE

    // epilogue: bias + activation + bf16 stores
#pragma unroll
    for (int mi = 0; mi < 8; mi++) {
#pragma unroll
        for (int ni = 0; ni < 4; ni++) {
            const int nb = wc * 64 + ni * 16 + l15;
            const float bv = bptr[nb];
            const int rl = wr * 128 + mi * 16 + lh * 4;
#pragma unroll
            for (int r = 0; r < 4; r++) {
                if (rl + r < Mvalid) {
                    float y = acc[mi][ni][r] + bv;
                    float a = use_tanh ? fast_tanh(y) : fast_sigmoid(y);
                    dst[(size_t)(rowbase + rl + r) * HID + colbase + nb] = f2b(a);
                }
            }
        }
    }
}

// ---- kernel 4: fo-pool scan over T; h = o_last * c_last ----
__global__ __launch_bounds__(256) void fo_pool(
    const unsigned* __restrict__ z32, const unsigned* __restrict__ fz32,
    const unsigned* __restrict__ o32, float* __restrict__ hbuf)
{
    const int p = blockIdx.x * 256 + threadIdx.x;  // pairs of h
    float c0 = 0.f, c1 = 0.f;
#pragma unroll 8
    for (int t = 0; t < T_LEN; ++t) {
        unsigned zz = z32[(size_t)t * (B_DIM * HID / 2) + p];
        unsigned ff = fz32[(size_t)t * (B_DIM * HID / 2) + p];
        float z0 = b2f((ushort)(zz & 0xffffu)), z1 = b2f((ushort)(zz >> 16));
        float f0 = b2f((ushort)(ff & 0xffffu)), f1 = b2f((ushort)(ff >> 16));
        c0 += f0 * (z0 - c0);
        c1 += f1 * (z1 - c1);
    }
    unsigned oo = o32[p];
    float o0 = b2f((ushort)(oo & 0xffffu)), o1 = b2f((ushort)(oo >> 16));
    hbuf[2 * p]     = o0 * c0;
    hbuf[2 * p + 1] = o1 * c1;
}

// ---- kernel 5: logits = h @ Wout + bout; log_softmax ----
__global__ __launch_bounds__(64) void classify(
    const float* __restrict__ hbuf, const float* __restrict__ Wout,
    const float* __restrict__ bout, float* __restrict__ out)
{
    __shared__ float hs[HID];
    const int b = blockIdx.x, l = threadIdx.x;
#pragma unroll
    for (int j = 0; j < HID; j += 64) hs[j + l] = hbuf[(size_t)b * HID + j + l];
    __syncthreads();
    float acc = -1e30f;
    if (l < NLAB) {
        float s = bout[l];
#pragma unroll 4
        for (int e = 0; e < HID; e++) s += hs[e] * Wout[(size_t)e * NLAB + l];
        acc = s;
    }
    float m = acc;
#pragma unroll
    for (int off = 32; off; off >>= 1) m = fmaxf(m, __shfl_xor(m, off));
    float ex = (l < NLAB) ? expf(acc - m) : 0.f;
    float sum = ex;
#pragma unroll
    for (int off = 32; off; off >>= 1) sum += __shfl_xor(sum, off);
    if (l < NLAB) out[(size_t)b * NLAB + l] = acc - m - logf(sum);
}

extern "C" void kernel_launch(void* const* d_in, const int* in_sizes, int n_in,
                              void* d_out, int out_size, void* d_ws, size_t ws_size,
                              hipStream_t stream) {
    const int* sent = (const int*)d_in[0];
    const float* emb = (const float*)d_in[1];
    const float* W = (const float*)d_in[2];
    const float* bias = (const float*)d_in[3];
    const float* Wout = (const float*)d_in[4];
    const float* bout = (const float*)d_in[5];
    float* out = (float*)d_out;

    ushort* xb = (ushort*)d_ws;                      // 32768*1024 bf16
    ushort* Wt = xb + (size_t)M_ROWS * EMB;          // 3072*1024 bf16
    ushort* zb = Wt + (size_t)N3H * EMB;             // 32768*1024 bf16
    ushort* fb = zb + (size_t)M_ROWS * HID;          // 32768*1024 bf16
    ushort* ob = fb + (size_t)M_ROWS * HID;          // 128*1024 bf16
    float* hb = (float*)(ob + (size_t)B_DIM * HID);  // 128*1024 f32

    hipLaunchKernelGGL(gather_convert, dim3(M_ROWS / 16), dim3(256), 0, stream,
                       sent, emb, xb);
    hipLaunchKernelGGL(transposeW, dim3(N3H / 32, EMB / 32), dim3(32, 8), 0, stream,
                       W, Wt);
    hipLaunchKernelGGL(gemm256, dim3(1024 + 4), dim3(512), 0, stream,
                       xb, Wt, bias, zb, fb, ob);
    hipLaunchKernelGGL(fo_pool, dim3(B_DIM * HID / 2 / 256), dim3(256), 0, stream,
                       (const unsigned*)zb, (const unsigned*)fb,
                       (const unsigned*)ob, hb);
    hipLaunchKernelGGL(classify, dim3(B_DIM), dim3(64), 0, stream,
                       hb, Wout, bout, out);
}

// Round 7
// 408.685 us; speedup vs baseline: 1.2375x; 1.2375x over previous
//
#include <hip/hip_runtime.h>
#include <hip/hip_bf16.h>

#define T_LEN 256
#define B_DIM 128
#define EMB 1024
#define HID 1024
#define NLAB 50
#define M_ROWS (T_LEN * B_DIM)   // 32768
#define N3H 3072
#define KT 16                    // 1024 / BK=64

typedef __attribute__((ext_vector_type(8))) short short8;
typedef __attribute__((ext_vector_type(4))) float f32x4;

// ---- helpers ----
static __device__ __forceinline__ ushort f2b(float x) {
    unsigned u = __builtin_bit_cast(unsigned, x);
    unsigned lsb = (u >> 16) & 1u;
    u += 0x7fffu + lsb;
    return (ushort)(u >> 16);
}
static __device__ __forceinline__ float b2f(ushort u) {
    unsigned v = ((unsigned)u) << 16;
    return __builtin_bit_cast(float, v);
}
static __device__ __forceinline__ void gload16(const ushort* g, ushort* l) {
    __builtin_amdgcn_global_load_lds(
        (const __attribute__((address_space(1))) unsigned int*)g,
        (__attribute__((address_space(3))) unsigned int*)l,
        16, 0, 0);
}
static __device__ __forceinline__ float fast_sigmoid(float y) {
    return 1.f / (1.f + __expf(-y));
}
static __device__ __forceinline__ float fast_tanh(float y) {
    float e = __expf(2.f * y);
    return (e - 1.f) / (e + 1.f);
}

// ---- kernel 1: x = bf16(emb[sentence]), 16 rows per block ----
__global__ __launch_bounds__(256) void gather_convert(
    const int* __restrict__ sent, const float* __restrict__ emb,
    ushort* __restrict__ xb)
{
    const int row = blockIdx.x * 16 + (threadIdx.x >> 4);
    const int seg = threadIdx.x & 15;
    const size_t src = (size_t)sent[row] * EMB;
    const float4* ep = (const float4*)(emb + src);
    ushort4* op = (ushort4*)(xb + (size_t)row * EMB);
#pragma unroll
    for (int j = 0; j < 16; j++) {
        float4 v = ep[seg + j * 16];
        ushort4 o;
        o.x = f2b(v.x); o.y = f2b(v.y); o.z = f2b(v.z); o.w = f2b(v.w);
        op[seg + j * 16] = o;
    }
}

// ---- kernel 2: Wt[n][k] = bf16(W[k][n]) ----
__global__ __launch_bounds__(256) void transposeW(
    const float* __restrict__ W, ushort* __restrict__ Wt)
{
    __shared__ float tile[32][33];
    const int n0 = blockIdx.x * 32, k0 = blockIdx.y * 32;
    const int tx = threadIdx.x, ty = threadIdx.y;   // 32 x 8
#pragma unroll
    for (int j = 0; j < 32; j += 8)
        tile[ty + j][tx] = W[(size_t)(k0 + ty + j) * N3H + n0 + tx];
    __syncthreads();
#pragma unroll
    for (int j = 0; j < 32; j += 8)
        Wt[(size_t)(n0 + ty + j) * EMB + k0 + tx] = f2b(tile[tx][ty + j]);
}

// ---- kernel 3: 256x256, BK=64, 8 waves, 2-phase; ROW-MAJOR LDS + XOR swizzle ----
// LDS tile: [256 rows][64 k] bf16 (32 KB). Row = 8 granules of 16B.
// Granule g of row r stored at slot g^(r&7)  (involution, within-row).
// Stage: linear LDS dest (chunk c), source granule = (c&7)^(row&7) -> the
// permutation stays inside the row's 128B => global reads remain coalesced
// (8 lanes cover one row's 2 cache lines; wave touches 16 lines, not 64).
// Read: lane(l15,lh), k-octet o=ks*4+lh at row R: slot o^(R&7); R&7==l15&7 so
// the swizzle term is mi/ni-independent -> one base addr per ks per matrix.
__global__ __launch_bounds__(512) void gemm256(
    const ushort* __restrict__ A, const ushort* __restrict__ Bt,
    const float* __restrict__ bias,
    ushort* __restrict__ zb, ushort* __restrict__ fb, ushort* __restrict__ ob)
{
    __shared__ ushort LDS[2 * 32768];   // 2 bufs x (A 32KB + B 32KB) = 128 KB

    const int tid = threadIdx.x;
    const int lane = tid & 63;
    const int w = tid >> 6;
    const int wr = w >> 2, wc = w & 3;          // 2 x 4 wave grid, wave-tile 128x64
    const int l15 = lane & 15, lh = lane >> 4;

    const int wg = blockIdx.x;
    const ushort *Ab, *Bb;
    const float* bptr;
    ushort* dst;
    int rowbase, colbase, Mvalid, maxrow;
    bool use_tanh;
    if (wg < 1024) {
        const int w2 = (wg & 7) * 128 + (wg >> 3);   // XCD-chunked, nt-fastest
        const int mt = w2 >> 3, nt = w2 & 7;
        Ab = A + (size_t)mt * 256 * EMB;
        Bb = Bt + (size_t)nt * 256 * EMB;
        bptr = bias + nt * 256;
        rowbase = mt * 256; Mvalid = 256; maxrow = 255;
        if (nt < 4) { dst = zb; colbase = nt * 256; use_tanh = true; }
        else        { dst = fb; colbase = nt * 256 - 1024; use_tanh = false; }
    } else {
        const int q = wg - 1024;
        Ab = A + (size_t)(M_ROWS - 128) * EMB;
        Bb = Bt + (size_t)(2048 + q * 256) * EMB;
        bptr = bias + 2048 + q * 256;
        rowbase = 0; colbase = q * 256; Mvalid = 128; maxrow = 127;
        dst = ob; use_tanh = false;
    }

    // stage-side: chunk c = q*512+tid; row = c>>3, lds-granule = c&7,
    // source granule = (c&7) ^ (row&7)
    const ushort* gA[4];
    const ushort* gB[4];
    int dOf[4];
#pragma unroll
    for (int q = 0; q < 4; q++) {
        const int c = q * 512 + tid;
        const int row = c >> 3;
        const int gsrc = (c & 7) ^ (row & 7);
        gA[q] = Ab + (size_t)min(row, maxrow) * EMB + gsrc * 8;
        gB[q] = Bb + (size_t)row * EMB + gsrc * 8;
        dOf[q] = c * 8;
    }

#define STAGE(bp_, kt_) do {                                  \
        ushort* la_ = &LDS[(bp_) * 32768];                    \
        ushort* lb_ = la_ + 16384;                            \
        const int ko_ = (kt_) * 64;                           \
        gload16(gA[0] + ko_, la_ + dOf[0]);                   \
        gload16(gA[1] + ko_, la_ + dOf[1]);                   \
        gload16(gA[2] + ko_, la_ + dOf[2]);                   \
        gload16(gA[3] + ko_, la_ + dOf[3]);                   \
        gload16(gB[0] + ko_, lb_ + dOf[0]);                   \
        gload16(gB[1] + ko_, lb_ + dOf[1]);                   \
        gload16(gB[2] + ko_, lb_ + dOf[2]);                   \
        gload16(gB[3] + ko_, lb_ + dOf[3]);                   \
    } while (0)

    // read-side base offsets (ushort units); + mi*1024 / + ni*1024
    const int swz0 = (lh ^ (l15 & 7)) * 8;         // ks=0: octet lh
    const int swz1 = ((4 + lh) ^ (l15 & 7)) * 8;   // ks=1: octet 4+lh
    const int aRow = (wr * 128 + l15) * 64;
    const int bRow = (wc * 64 + l15) * 64 + 16384;
    const int adA0 = aRow + swz0, adA1 = aRow + swz1;
    const int adB0 = bRow + swz0, adB1 = bRow + swz1;

    f32x4 acc[8][4] = {};

    STAGE(0, 0);
    asm volatile("s_waitcnt vmcnt(0)" ::: "memory");
    __builtin_amdgcn_s_barrier();

#define MQ(AI, ar)                                                                   \
    acc[AI][0] = __builtin_amdgcn_mfma_f32_16x16x32_bf16(ar, b0, acc[AI][0], 0,0,0); \
    acc[AI][1] = __builtin_amdgcn_mfma_f32_16x16x32_bf16(ar, b1, acc[AI][1], 0,0,0); \
    acc[AI][2] = __builtin_amdgcn_mfma_f32_16x16x32_bf16(ar, b2, acc[AI][2], 0,0,0); \
    acc[AI][3] = __builtin_amdgcn_mfma_f32_16x16x32_bf16(ar, b3, acc[AI][3], 0,0,0);

#pragma unroll 1
    for (int t = 0; t < KT; ++t) {
        const int buf = t & 1;
        if (t + 1 < KT) STAGE(buf ^ 1, t + 1);   // issue next tile first

        const ushort* Ablk = &LDS[buf * 32768];

        // ---- ks = 0 ----
        {
            short8 a0 = *(const short8*)&Ablk[adA0];
            short8 a1 = *(const short8*)&Ablk[adA0 + 1024];
            short8 a2 = *(const short8*)&Ablk[adA0 + 2048];
            short8 a3 = *(const short8*)&Ablk[adA0 + 3072];
            short8 a4 = *(const short8*)&Ablk[adA0 + 4096];
            short8 a5 = *(const short8*)&Ablk[adA0 + 5120];
            short8 a6 = *(const short8*)&Ablk[adA0 + 6144];
            short8 a7 = *(const short8*)&Ablk[adA0 + 7168];
            short8 b0 = *(const short8*)&Ablk[adB0];
            short8 b1 = *(const short8*)&Ablk[adB0 + 1024];
            short8 b2 = *(const short8*)&Ablk[adB0 + 2048];
            short8 b3 = *(const short8*)&Ablk[adB0 + 3072];
            asm volatile("s_waitcnt lgkmcnt(0)" ::: "memory");
            __builtin_amdgcn_s_setprio(1);
            MQ(0, a0) MQ(1, a1) MQ(2, a2) MQ(3, a3)
            MQ(4, a4) MQ(5, a5) MQ(6, a6) MQ(7, a7)
            __builtin_amdgcn_s_setprio(0);
        }
        // ---- ks = 1 ----
        {
            short8 a0 = *(const short8*)&Ablk[adA1];
            short8 a1 = *(const short8*)&Ablk[adA1 + 1024];
            short8 a2 = *(const short8*)&Ablk[adA1 + 2048];
            short8 a3 = *(const short8*)&Ablk[adA1 + 3072];
            short8 a4 = *(const short8*)&Ablk[adA1 + 4096];
            short8 a5 = *(const short8*)&Ablk[adA1 + 5120];
            short8 a6 = *(const short8*)&Ablk[adA1 + 6144];
            short8 a7 = *(const short8*)&Ablk[adA1 + 7168];
            short8 b0 = *(const short8*)&Ablk[adB1];
            short8 b1 = *(const short8*)&Ablk[adB1 + 1024];
            short8 b2 = *(const short8*)&Ablk[adB1 + 2048];
            short8 b3 = *(const short8*)&Ablk[adB1 + 3072];
            asm volatile("s_waitcnt lgkmcnt(0)" ::: "memory");
            __builtin_amdgcn_s_setprio(1);
            MQ(0, a0) MQ(1, a1) MQ(2, a2) MQ(3, a3)
            MQ(4, a4) MQ(5, a5) MQ(6, a6) MQ(7, a7)
            __builtin_amdgcn_s_setprio(0);
        }

        if (t + 1 < KT) {
            asm volatile("s_waitcnt vmcnt(0)" ::: "memory");
            __builtin_amdgcn_s_barrier();
        }
    }
#undef MQ
#undef STAGE

    // epilogue: bias + activation + bf16 stores
#pragma unroll
    for (int mi = 0; mi < 8; mi++) {
#pragma unroll
        for (int ni = 0; ni < 4; ni++) {
            const int nb = wc * 64 + ni * 16 + l15;
            const float bv = bptr[nb];
            const int rl = wr * 128 + mi * 16 + lh * 4;
#pragma unroll
            for (int r = 0; r < 4; r++) {
                if (rl + r < Mvalid) {
                    float y = acc[mi][ni][r] + bv;
                    float a = use_tanh ? fast_tanh(y) : fast_sigmoid(y);
                    dst[(size_t)(rowbase + rl + r) * HID + colbase + nb] = f2b(a);
                }
            }
        }
    }
}

// ---- kernel 4: fo-pool scan over T; h = o_last * c_last ----
__global__ __launch_bounds__(256) void fo_pool(
    const unsigned* __restrict__ z32, const unsigned* __restrict__ fz32,
    const unsigned* __restrict__ o32, float* __restrict__ hbuf)
{
    const int p = blockIdx.x * 256 + threadIdx.x;  // pairs of h
    float c0 = 0.f, c1 = 0.f;
#pragma unroll 8
    for (int t = 0; t < T_LEN; ++t) {
        unsigned zz = z32[(size_t)t * (B_DIM * HID / 2) + p];
        unsigned ff = fz32[(size_t)t * (B_DIM * HID / 2) + p];
        float z0 = b2f((ushort)(zz & 0xffffu)), z1 = b2f((ushort)(zz >> 16));
        float f0 = b2f((ushort)(ff & 0xffffu)), f1 = b2f((ushort)(ff >> 16));
        c0 += f0 * (z0 - c0);
        c1 += f1 * (z1 - c1);
    }
    unsigned oo = o32[p];
    float o0 = b2f((ushort)(oo & 0xffffu)), o1 = b2f((ushort)(oo >> 16));
    hbuf[2 * p]     = o0 * c0;
    hbuf[2 * p + 1] = o1 * c1;
}

// ---- kernel 5: logits = h @ Wout + bout; log_softmax ----
__global__ __launch_bounds__(64) void classify(
    const float* __restrict__ hbuf, const float* __restrict__ Wout,
    const float* __restrict__ bout, float* __restrict__ out)
{
    __shared__ float hs[HID];
    const int b = blockIdx.x, l = threadIdx.x;
#pragma unroll
    for (int j = 0; j < HID; j += 64) hs[j + l] = hbuf[(size_t)b * HID + j + l];
    __syncthreads();
    float acc = -1e30f;
    if (l < NLAB) {
        float s = bout[l];
#pragma unroll 4
        for (int e = 0; e < HID; e++) s += hs[e] * Wout[(size_t)e * NLAB + l];
        acc = s;
    }
    float m = acc;
#pragma unroll
    for (int off = 32; off; off >>= 1) m = fmaxf(m, __shfl_xor(m, off));
    float ex = (l < NLAB) ? expf(acc - m) : 0.f;
    float sum = ex;
#pragma unroll
    for (int off = 32; off; off >>= 1) sum += __shfl_xor(sum, off);
    if (l < NLAB) out[(size_t)b * NLAB + l] = acc - m - logf(sum);
}

extern "C" void kernel_launch(void* const* d_in, const int* in_sizes, int n_in,
                              void* d_out, int out_size, void* d_ws, size_t ws_size,
                              hipStream_t stream) {
    const int* sent = (const int*)d_in[0];
    const float* emb = (const float*)d_in[1];
    const float* W = (const float*)d_in[2];
    const float* bias = (const float*)d_in[3];
    const float* Wout = (const float*)d_in[4];
    const float* bout = (const float*)d_in[5];
    float* out = (float*)d_out;

    ushort* xb = (ushort*)d_ws;                      // 32768*1024 bf16
    ushort* Wt = xb + (size_t)M_ROWS * EMB;          // 3072*1024 bf16
    ushort* zb = Wt + (size_t)N3H * EMB;             // 32768*1024 bf16
    ushort* fb = zb + (size_t)M_ROWS * HID;          // 32768*1024 bf16
    ushort* ob = fb + (size_t)M_ROWS * HID;          // 128*1024 bf16
    float* hb = (float*)(ob + (size_t)B_DIM * HID);  // 128*1024 f32

    hipLaunchKernelGGL(gather_convert, dim3(M_ROWS / 16), dim3(256), 0, stream,
                       sent, emb, xb);
    hipLaunchKernelGGL(transposeW, dim3(N3H / 32, EMB / 32), dim3(32, 8), 0, stream,
                       W, Wt);
    hipLaunchKernelGGL(gemm256, dim3(1024 + 4), dim3(512), 0, stream,
                       xb, Wt, bias, zb, fb, ob);
    hipLaunchKernelGGL(fo_pool, dim3(B_DIM * HID / 2 / 256), dim3(256), 0, stream,
                       (const unsigned*)zb, (const unsigned*)fb,
                       (const unsigned*)ob, hb);
    hipLaunchKernelGGL(classify, dim3(B_DIM), dim3(64), 0, stream,
                       hb, Wout, bout, out);
}

// Round 8
// 352.544 us; speedup vs baseline: 1.4346x; 1.1592x over previous
//
#include <hip/hip_runtime.h>
#include <hip/hip_bf16.h>

#define T_LEN 256
#define B_DIM 128
#define EMB 1024
#define HID 1024
#define NLAB 50
#define M_ROWS (T_LEN * B_DIM)   // 32768
#define N3H 3072
#define KT 32                    // 1024 / BK=32

typedef __attribute__((ext_vector_type(8))) short short8;
typedef __attribute__((ext_vector_type(4))) float f32x4;

// ---- helpers ----
static __device__ __forceinline__ ushort f2b(float x) {
    unsigned u = __builtin_bit_cast(unsigned, x);
    unsigned lsb = (u >> 16) & 1u;
    u += 0x7fffu + lsb;
    return (ushort)(u >> 16);
}
static __device__ __forceinline__ float b2f(ushort u) {
    unsigned v = ((unsigned)u) << 16;
    return __builtin_bit_cast(float, v);
}
static __device__ __forceinline__ void gload16(const ushort* g, ushort* l) {
    __builtin_amdgcn_global_load_lds(
        (const __attribute__((address_space(1))) unsigned int*)g,
        (__attribute__((address_space(3))) unsigned int*)l,
        16, 0, 0);
}
static __device__ __forceinline__ float fast_sigmoid(float y) {
    return 1.f / (1.f + __expf(-y));
}
static __device__ __forceinline__ float fast_tanh(float y) {
    float e = __expf(2.f * y);
    return (e - 1.f) / (e + 1.f);
}

// ---- kernel 1: x = bf16(emb[sentence]), 16 rows per block ----
__global__ __launch_bounds__(256) void gather_convert(
    const int* __restrict__ sent, const float* __restrict__ emb,
    ushort* __restrict__ xb)
{
    const int row = blockIdx.x * 16 + (threadIdx.x >> 4);
    const int seg = threadIdx.x & 15;
    const size_t src = (size_t)sent[row] * EMB;
    const float4* ep = (const float4*)(emb + src);
    ushort4* op = (ushort4*)(xb + (size_t)row * EMB);
#pragma unroll
    for (int j = 0; j < 16; j++) {
        float4 v = ep[seg + j * 16];
        ushort4 o;
        o.x = f2b(v.x); o.y = f2b(v.y); o.z = f2b(v.z); o.w = f2b(v.w);
        op[seg + j * 16] = o;
    }
}

// ---- kernel 2: Wt[n][k] = bf16(W[k][n]) ----
__global__ __launch_bounds__(256) void transposeW(
    const float* __restrict__ W, ushort* __restrict__ Wt)
{
    __shared__ float tile[32][33];
    const int n0 = blockIdx.x * 32, k0 = blockIdx.y * 32;
    const int tx = threadIdx.x, ty = threadIdx.y;   // 32 x 8
#pragma unroll
    for (int j = 0; j < 32; j += 8)
        tile[ty + j][tx] = W[(size_t)(k0 + ty + j) * N3H + n0 + tx];
    __syncthreads();
#pragma unroll
    for (int j = 0; j < 32; j += 8)
        Wt[(size_t)(n0 + ty + j) * EMB + k0 + tx] = f2b(tile[tx][ty + j]);
}

// ---- kernel 3: m97-structure 128x128 GEMM, BK=32, 4 waves, single-buffer ----
// LDS: row-major [128][32] bf16 per matrix (8 KB each). Staging chunk c
// (row=c>>2, granule=c&3) is LINEAR row-major -> global_load_lds dest ok AND
// global source coalesced (lanes 0-3 = one row's 64B line). Frag read: lane
// (l15,lh) reads row base+l15, k-octet lh -> wave covers contiguous 1KB, 2
// lanes/bank (free). No swizzle needed at 64B row stride.
// Grid: 4096 main z/f blocks + 8 o-gate blocks (exactly 128 valid rows).
// Occupancy ~3 blocks/CU provides the latency hiding (m114/m97).
__global__ __launch_bounds__(256) void gemm128(
    const ushort* __restrict__ A, const ushort* __restrict__ Bt,
    const float* __restrict__ bias,
    ushort* __restrict__ zb, ushort* __restrict__ fb, ushort* __restrict__ ob)
{
    __shared__ ushort LA[128 * 32];   // 8 KB
    __shared__ ushort LB[128 * 32];   // 8 KB

    const int tid = threadIdx.x;
    const int lane = tid & 63;
    const int w = tid >> 6;
    const int wr = w >> 1, wc = w & 1;          // 2x2 wave grid, wave-tile 64x64
    const int l15 = lane & 15, lh = lane >> 4;

    const int wg = blockIdx.x;
    const ushort *Ab, *Bb;
    const float* bptr;
    ushort* dst;
    int rowbase, colbase;
    bool use_tanh;
    if (wg < 4096) {
        // XCD-chunked bijective swizzle (4096 % 8 == 0), nt-fastest:
        // 16 consecutive blocks on one XCD share the same A-panel (L2 reuse).
        const int w2 = (wg & 7) * 512 + (wg >> 3);
        const int mt = w2 >> 4, nt = w2 & 15;
        Ab = A + (size_t)mt * 128 * EMB;
        Bb = Bt + (size_t)nt * 128 * EMB;
        bptr = bias + nt * 128;
        rowbase = mt * 128;
        if (nt < 8) { dst = zb; colbase = nt * 128; use_tanh = true; }
        else        { dst = fb; colbase = (nt - 8) * 128; use_tanh = false; }
    } else {
        // o-gate: last 128 rows x cols 2048 + q*128 (all rows valid, no mask)
        const int q = wg - 4096;
        Ab = A + (size_t)(M_ROWS - 128) * EMB;
        Bb = Bt + (size_t)(2048 + q * 128) * EMB;
        bptr = bias + 2048 + q * 128;
        rowbase = 0; colbase = q * 128;
        dst = ob; use_tanh = false;
    }

    // stage-side: chunks c0=tid, c1=tid+256 per matrix; row=c>>2, g=c&3
    const int r0 = tid >> 2, g0 = tid & 3;
    const int r1 = (tid + 256) >> 2, g1 = tid & 3;
    const ushort* gA0 = Ab + (size_t)r0 * EMB + g0 * 8;
    const ushort* gA1 = Ab + (size_t)r1 * EMB + g1 * 8;
    const ushort* gB0 = Bb + (size_t)r0 * EMB + g0 * 8;
    const ushort* gB1 = Bb + (size_t)r1 * EMB + g1 * 8;
    ushort* lA0 = LA + tid * 8;
    ushort* lA1 = LA + (tid + 256) * 8;
    ushort* lB0 = LB + tid * 8;
    ushort* lB1 = LB + (tid + 256) * 8;

    // read-side offsets (ushort units): row-major [128][32]
    int adA[4], adB[4];
#pragma unroll
    for (int mi = 0; mi < 4; mi++)
        adA[mi] = (wr * 64 + mi * 16 + l15) * 32 + lh * 8;
#pragma unroll
    for (int ni = 0; ni < 4; ni++)
        adB[ni] = (wc * 64 + ni * 16 + l15) * 32 + lh * 8;

    f32x4 acc[4][4] = {};

    for (int kk = 0; kk < KT; ++kk) {
        const int ko = kk * 32;
        gload16(gA0 + ko, lA0);
        gload16(gA1 + ko, lA1);
        gload16(gB0 + ko, lB0);
        gload16(gB1 + ko, lB1);
        __syncthreads();

        short8 af[4], bf[4];
#pragma unroll
        for (int i = 0; i < 4; i++) {
            af[i] = *(const short8*)&LA[adA[i]];
            bf[i] = *(const short8*)&LB[adB[i]];
        }
#pragma unroll
        for (int mi = 0; mi < 4; mi++)
#pragma unroll
            for (int ni = 0; ni < 4; ni++)
                acc[mi][ni] = __builtin_amdgcn_mfma_f32_16x16x32_bf16(
                    af[mi], bf[ni], acc[mi][ni], 0, 0, 0);
        __syncthreads();
    }

    // epilogue: bias + activation + bf16 stores
#pragma unroll
    for (int mi = 0; mi < 4; mi++) {
#pragma unroll
        for (int ni = 0; ni < 4; ni++) {
            const int nb = wc * 64 + ni * 16 + l15;
            const float bv = bptr[nb];
            const int rl = wr * 64 + mi * 16 + lh * 4;
#pragma unroll
            for (int r = 0; r < 4; r++) {
                float y = acc[mi][ni][r] + bv;
                float a = use_tanh ? fast_tanh(y) : fast_sigmoid(y);
                dst[(size_t)(rowbase + rl + r) * HID + colbase + nb] = f2b(a);
            }
        }
    }
}

// ---- kernel 4: fo-pool scan over T; h = o_last * c_last ----
__global__ __launch_bounds__(256) void fo_pool(
    const unsigned* __restrict__ z32, const unsigned* __restrict__ fz32,
    const unsigned* __restrict__ o32, float* __restrict__ hbuf)
{
    const int p = blockIdx.x * 256 + threadIdx.x;  // pairs of h
    float c0 = 0.f, c1 = 0.f;
#pragma unroll 8
    for (int t = 0; t < T_LEN; ++t) {
        unsigned zz = z32[(size_t)t * (B_DIM * HID / 2) + p];
        unsigned ff = fz32[(size_t)t * (B_DIM * HID / 2) + p];
        float z0 = b2f((ushort)(zz & 0xffffu)), z1 = b2f((ushort)(zz >> 16));
        float f0 = b2f((ushort)(ff & 0xffffu)), f1 = b2f((ushort)(ff >> 16));
        c0 += f0 * (z0 - c0);
        c1 += f1 * (z1 - c1);
    }
    unsigned oo = o32[p];
    float o0 = b2f((ushort)(oo & 0xffffu)), o1 = b2f((ushort)(oo >> 16));
    hbuf[2 * p]     = o0 * c0;
    hbuf[2 * p + 1] = o1 * c1;
}

// ---- kernel 5: logits = h @ Wout + bout; log_softmax ----
__global__ __launch_bounds__(64) void classify(
    const float* __restrict__ hbuf, const float* __restrict__ Wout,
    const float* __restrict__ bout, float* __restrict__ out)
{
    __shared__ float hs[HID];
    const int b = blockIdx.x, l = threadIdx.x;
#pragma unroll
    for (int j = 0; j < HID; j += 64) hs[j + l] = hbuf[(size_t)b * HID + j + l];
    __syncthreads();
    float acc = -1e30f;
    if (l < NLAB) {
        float s = bout[l];
#pragma unroll 4
        for (int e = 0; e < HID; e++) s += hs[e] * Wout[(size_t)e * NLAB + l];
        acc = s;
    }
    float m = acc;
#pragma unroll
    for (int off = 32; off; off >>= 1) m = fmaxf(m, __shfl_xor(m, off));
    float ex = (l < NLAB) ? expf(acc - m) : 0.f;
    float sum = ex;
#pragma unroll
    for (int off = 32; off; off >>= 1) sum += __shfl_xor(sum, off);
    if (l < NLAB) out[(size_t)b * NLAB + l] = acc - m - logf(sum);
}

extern "C" void kernel_launch(void* const* d_in, const int* in_sizes, int n_in,
                              void* d_out, int out_size, void* d_ws, size_t ws_size,
                              hipStream_t stream) {
    const int* sent = (const int*)d_in[0];
    const float* emb = (const float*)d_in[1];
    const float* W = (const float*)d_in[2];
    const float* bias = (const float*)d_in[3];
    const float* Wout = (const float*)d_in[4];
    const float* bout = (const float*)d_in[5];
    float* out = (float*)d_out;

    ushort* xb = (ushort*)d_ws;                      // 32768*1024 bf16
    ushort* Wt = xb + (size_t)M_ROWS * EMB;          // 3072*1024 bf16
    ushort* zb = Wt + (size_t)N3H * EMB;             // 32768*1024 bf16
    ushort* fb = zb + (size_t)M_ROWS * HID;          // 32768*1024 bf16
    ushort* ob = fb + (size_t)M_ROWS * HID;          // 128*1024 bf16
    float* hb = (float*)(ob + (size_t)B_DIM * HID);  // 128*1024 f32

    hipLaunchKernelGGL(gather_convert, dim3(M_ROWS / 16), dim3(256), 0, stream,
                       sent, emb, xb);
    hipLaunchKernelGGL(transposeW, dim3(N3H / 32, EMB / 32), dim3(32, 8), 0, stream,
                       W, Wt);
    hipLaunchKernelGGL(gemm128, dim3(4096 + 8), dim3(256), 0, stream,
                       xb, Wt, bias, zb, fb, ob);
    hipLaunchKernelGGL(fo_pool, dim3(B_DIM * HID / 2 / 256), dim3(256), 0, stream,
                       (const unsigned*)zb, (const unsigned*)fb,
                       (const unsigned*)ob, hb);
    hipLaunchKernelGGL(classify, dim3(B_DIM), dim3(64), 0, stream,
                       hb, Wout, bout, out);
}

// Round 9
// 324.678 us; speedup vs baseline: 1.5577x; 1.0858x over previous
//
#include <hip/hip_runtime.h>
#include <hip/hip_bf16.h>

#define T_LEN 256
#define B_DIM 128
#define EMB 1024
#define HID 1024
#define NLAB 50
#define M_ROWS (T_LEN * B_DIM)   // 32768
#define N3H 3072
#define KT 16                    // 1024 / BK=64

typedef __attribute__((ext_vector_type(8))) short short8;
typedef __attribute__((ext_vector_type(4))) float f32x4;

// ---- helpers ----
static __device__ __forceinline__ ushort f2b(float x) {
    unsigned u = __builtin_bit_cast(unsigned, x);
    unsigned lsb = (u >> 16) & 1u;
    u += 0x7fffu + lsb;
    return (ushort)(u >> 16);
}
static __device__ __forceinline__ float b2f(ushort u) {
    unsigned v = ((unsigned)u) << 16;
    return __builtin_bit_cast(float, v);
}
static __device__ __forceinline__ void gload16(const ushort* g, ushort* l) {
    __builtin_amdgcn_global_load_lds(
        (const __attribute__((address_space(1))) unsigned int*)g,
        (__attribute__((address_space(3))) unsigned int*)l,
        16, 0, 0);
}
static __device__ __forceinline__ float fast_sigmoid(float y) {
    return 1.f / (1.f + __expf(-y));
}
static __device__ __forceinline__ float fast_tanh(float y) {
    float e = __expf(2.f * y);
    return (e - 1.f) / (e + 1.f);
}

// ---- kernel 1: x = bf16(emb[sentence]), 16 rows per block ----
__global__ __launch_bounds__(256) void gather_convert(
    const int* __restrict__ sent, const float* __restrict__ emb,
    ushort* __restrict__ xb)
{
    const int row = blockIdx.x * 16 + (threadIdx.x >> 4);
    const int seg = threadIdx.x & 15;
    const size_t src = (size_t)sent[row] * EMB;
    const float4* ep = (const float4*)(emb + src);
    ushort4* op = (ushort4*)(xb + (size_t)row * EMB);
#pragma unroll
    for (int j = 0; j < 16; j++) {
        float4 v = ep[seg + j * 16];
        ushort4 o;
        o.x = f2b(v.x); o.y = f2b(v.y); o.z = f2b(v.z); o.w = f2b(v.w);
        op[seg + j * 16] = o;
    }
}

// ---- kernel 2: Wt[n][k] = bf16(W[k][n]) ----
__global__ __launch_bounds__(256) void transposeW(
    const float* __restrict__ W, ushort* __restrict__ Wt)
{
    __shared__ float tile[32][33];
    const int n0 = blockIdx.x * 32, k0 = blockIdx.y * 32;
    const int tx = threadIdx.x, ty = threadIdx.y;   // 32 x 8
#pragma unroll
    for (int j = 0; j < 32; j += 8)
        tile[ty + j][tx] = W[(size_t)(k0 + ty + j) * N3H + n0 + tx];
    __syncthreads();
#pragma unroll
    for (int j = 0; j < 32; j += 8)
        Wt[(size_t)(n0 + ty + j) * EMB + k0 + tx] = f2b(tile[tx][ty + j]);
}

// ---- kernel 3: m97-structure 128x128 GEMM, BK=64, 4 waves, single-buffer ----
// LDS: row-major [128][64] bf16 per matrix (16 KB each). Rows are 128B = 8
// granules of 16B; granule g of row r stored at slot g^(r&7) (involution).
// Staging: linear LDS dest (chunk c = row*8+slot), global source granule
// (c&7)^(row&7) -> permutation stays within the row's 128B, coalesced.
// Read: lane (l15,lh), k-octet o=ks*4+lh at row R: slot o^(R&7). R&7==l15&7,
// so swizzle term is mi/ni-independent. 16 consecutive rows spread across all
// 32 banks -> conflict-free (verified 0 conflicts with this scheme in R6).
__global__ __launch_bounds__(256) void gemm128(
    const ushort* __restrict__ A, const ushort* __restrict__ Bt,
    const float* __restrict__ bias,
    ushort* __restrict__ zb, ushort* __restrict__ fb, ushort* __restrict__ ob)
{
    __shared__ ushort LA[128 * 64];   // 16 KB
    __shared__ ushort LB[128 * 64];   // 16 KB

    const int tid = threadIdx.x;
    const int lane = tid & 63;
    const int w = tid >> 6;
    const int wr = w >> 1, wc = w & 1;          // 2x2 wave grid, wave-tile 64x64
    const int l15 = lane & 15, lh = lane >> 4;

    const int wg = blockIdx.x;
    const ushort *Ab, *Bb;
    const float* bptr;
    ushort* dst;
    int rowbase, colbase;
    bool use_tanh;
    if (wg < 4096) {
        // XCD-chunked bijective swizzle (4096 % 8 == 0), nt-fastest:
        // 16 consecutive blocks on one XCD share the same A-panel (L2 reuse).
        const int w2 = (wg & 7) * 512 + (wg >> 3);
        const int mt = w2 >> 4, nt = w2 & 15;
        Ab = A + (size_t)mt * 128 * EMB;
        Bb = Bt + (size_t)nt * 128 * EMB;
        bptr = bias + nt * 128;
        rowbase = mt * 128;
        if (nt < 8) { dst = zb; colbase = nt * 128; use_tanh = true; }
        else        { dst = fb; colbase = (nt - 8) * 128; use_tanh = false; }
    } else {
        // o-gate: last 128 rows x cols 2048 + q*128 (all rows valid)
        const int q = wg - 4096;
        Ab = A + (size_t)(M_ROWS - 128) * EMB;
        Bb = Bt + (size_t)(2048 + q * 128) * EMB;
        bptr = bias + 2048 + q * 128;
        rowbase = 0; colbase = q * 128;
        dst = ob; use_tanh = false;
    }

    // stage-side: 4 chunks per matrix per thread; chunk c = q*256 + tid
    const ushort* gA[4];
    const ushort* gB[4];
    int dOf[4];
#pragma unroll
    for (int q = 0; q < 4; q++) {
        const int c = q * 256 + tid;
        const int row = c >> 3;
        const int gsrc = (c & 7) ^ (row & 7);
        gA[q] = Ab + (size_t)row * EMB + gsrc * 8;
        gB[q] = Bb + (size_t)row * EMB + gsrc * 8;
        dOf[q] = c * 8;
    }

    // read-side base offsets (ushort units); frag mi at +mi*1024
    const int swz0 = (lh ^ (l15 & 7)) * 8;         // ks=0: octet lh
    const int swz1 = ((4 + lh) ^ (l15 & 7)) * 8;   // ks=1: octet 4+lh
    const int aRow = (wr * 64 + l15) * 64;
    const int bRow = (wc * 64 + l15) * 64;

    f32x4 acc[4][4] = {};

    for (int kk = 0; kk < KT; ++kk) {
        const int ko = kk * 64;
        gload16(gA[0] + ko, LA + dOf[0]);
        gload16(gA[1] + ko, LA + dOf[1]);
        gload16(gA[2] + ko, LA + dOf[2]);
        gload16(gA[3] + ko, LA + dOf[3]);
        gload16(gB[0] + ko, LB + dOf[0]);
        gload16(gB[1] + ko, LB + dOf[1]);
        gload16(gB[2] + ko, LB + dOf[2]);
        gload16(gB[3] + ko, LB + dOf[3]);
        __syncthreads();

        // ks = 0
        {
            short8 a0 = *(const short8*)&LA[aRow + swz0];
            short8 a1 = *(const short8*)&LA[aRow + 1024 + swz0];
            short8 a2 = *(const short8*)&LA[aRow + 2048 + swz0];
            short8 a3 = *(const short8*)&LA[aRow + 3072 + swz0];
            short8 b0 = *(const short8*)&LB[bRow + swz0];
            short8 b1 = *(const short8*)&LB[bRow + 1024 + swz0];
            short8 b2 = *(const short8*)&LB[bRow + 2048 + swz0];
            short8 b3 = *(const short8*)&LB[bRow + 3072 + swz0];
#pragma unroll
            for (int mi = 0; mi < 4; mi++) {
                const short8 am = (mi == 0) ? a0 : (mi == 1) ? a1 : (mi == 2) ? a2 : a3;
                acc[mi][0] = __builtin_amdgcn_mfma_f32_16x16x32_bf16(am, b0, acc[mi][0], 0, 0, 0);
                acc[mi][1] = __builtin_amdgcn_mfma_f32_16x16x32_bf16(am, b1, acc[mi][1], 0, 0, 0);
                acc[mi][2] = __builtin_amdgcn_mfma_f32_16x16x32_bf16(am, b2, acc[mi][2], 0, 0, 0);
                acc[mi][3] = __builtin_amdgcn_mfma_f32_16x16x32_bf16(am, b3, acc[mi][3], 0, 0, 0);
            }
        }
        // ks = 1
        {
            short8 a0 = *(const short8*)&LA[aRow + swz1];
            short8 a1 = *(const short8*)&LA[aRow + 1024 + swz1];
            short8 a2 = *(const short8*)&LA[aRow + 2048 + swz1];
            short8 a3 = *(const short8*)&LA[aRow + 3072 + swz1];
            short8 b0 = *(const short8*)&LB[bRow + swz1];
            short8 b1 = *(const short8*)&LB[bRow + 1024 + swz1];
            short8 b2 = *(const short8*)&LB[bRow + 2048 + swz1];
            short8 b3 = *(const short8*)&LB[bRow + 3072 + swz1];
#pragma unroll
            for (int mi = 0; mi < 4; mi++) {
                const short8 am = (mi == 0) ? a0 : (mi == 1) ? a1 : (mi == 2) ? a2 : a3;
                acc[mi][0] = __builtin_amdgcn_mfma_f32_16x16x32_bf16(am, b0, acc[mi][0], 0, 0, 0);
                acc[mi][1] = __builtin_amdgcn_mfma_f32_16x16x32_bf16(am, b1, acc[mi][1], 0, 0, 0);
                acc[mi][2] = __builtin_amdgcn_mfma_f32_16x16x32_bf16(am, b2, acc[mi][2], 0, 0, 0);
                acc[mi][3] = __builtin_amdgcn_mfma_f32_16x16x32_bf16(am, b3, acc[mi][3], 0, 0, 0);
            }
        }
        __syncthreads();
    }

    // epilogue: bias + activation + bf16 stores
#pragma unroll
    for (int mi = 0; mi < 4; mi++) {
#pragma unroll
        for (int ni = 0; ni < 4; ni++) {
            const int nb = wc * 64 + ni * 16 + l15;
            const float bv = bptr[nb];
            const int rl = wr * 64 + mi * 16 + lh * 4;
#pragma unroll
            for (int r = 0; r < 4; r++) {
                float y = acc[mi][ni][r] + bv;
                float a = use_tanh ? fast_tanh(y) : fast_sigmoid(y);
                dst[(size_t)(rowbase + rl + r) * HID + colbase + nb] = f2b(a);
            }
        }
    }
}

// ---- kernel 4: fo-pool scan over T; h = o_last * c_last ----
__global__ __launch_bounds__(256) void fo_pool(
    const unsigned* __restrict__ z32, const unsigned* __restrict__ fz32,
    const unsigned* __restrict__ o32, float* __restrict__ hbuf)
{
    const int p = blockIdx.x * 256 + threadIdx.x;  // pairs of h
    float c0 = 0.f, c1 = 0.f;
#pragma unroll 8
    for (int t = 0; t < T_LEN; ++t) {
        unsigned zz = z32[(size_t)t * (B_DIM * HID / 2) + p];
        unsigned ff = fz32[(size_t)t * (B_DIM * HID / 2) + p];
        float z0 = b2f((ushort)(zz & 0xffffu)), z1 = b2f((ushort)(zz >> 16));
        float f0 = b2f((ushort)(ff & 0xffffu)), f1 = b2f((ushort)(ff >> 16));
        c0 += f0 * (z0 - c0);
        c1 += f1 * (z1 - c1);
    }
    unsigned oo = o32[p];
    float o0 = b2f((ushort)(oo & 0xffffu)), o1 = b2f((ushort)(oo >> 16));
    hbuf[2 * p]     = o0 * c0;
    hbuf[2 * p + 1] = o1 * c1;
}

// ---- kernel 5: logits = h @ Wout + bout; log_softmax ----
__global__ __launch_bounds__(64) void classify(
    const float* __restrict__ hbuf, const float* __restrict__ Wout,
    const float* __restrict__ bout, float* __restrict__ out)
{
    __shared__ float hs[HID];
    const int b = blockIdx.x, l = threadIdx.x;
#pragma unroll
    for (int j = 0; j < HID; j += 64) hs[j + l] = hbuf[(size_t)b * HID + j + l];
    __syncthreads();
    float acc = -1e30f;
    if (l < NLAB) {
        float s = bout[l];
#pragma unroll 4
        for (int e = 0; e < HID; e++) s += hs[e] * Wout[(size_t)e * NLAB + l];
        acc = s;
    }
    float m = acc;
#pragma unroll
    for (int off = 32; off; off >>= 1) m = fmaxf(m, __shfl_xor(m, off));
    float ex = (l < NLAB) ? expf(acc - m) : 0.f;
    float sum = ex;
#pragma unroll
    for (int off = 32; off; off >>= 1) sum += __shfl_xor(sum, off);
    if (l < NLAB) out[(size_t)b * NLAB + l] = acc - m - logf(sum);
}

extern "C" void kernel_launch(void* const* d_in, const int* in_sizes, int n_in,
                              void* d_out, int out_size, void* d_ws, size_t ws_size,
                              hipStream_t stream) {
    const int* sent = (const int*)d_in[0];
    const float* emb = (const float*)d_in[1];
    const float* W = (const float*)d_in[2];
    const float* bias = (const float*)d_in[3];
    const float* Wout = (const float*)d_in[4];
    const float* bout = (const float*)d_in[5];
    float* out = (float*)d_out;

    ushort* xb = (ushort*)d_ws;                      // 32768*1024 bf16
    ushort* Wt = xb + (size_t)M_ROWS * EMB;          // 3072*1024 bf16
    ushort* zb = Wt + (size_t)N3H * EMB;             // 32768*1024 bf16
    ushort* fb = zb + (size_t)M_ROWS * HID;          // 32768*1024 bf16
    ushort* ob = fb + (size_t)M_ROWS * HID;          // 128*1024 bf16
    float* hb = (float*)(ob + (size_t)B_DIM * HID);  // 128*1024 f32

    hipLaunchKernelGGL(gather_convert, dim3(M_ROWS / 16), dim3(256), 0, stream,
                       sent, emb, xb);
    hipLaunchKernelGGL(transposeW, dim3(N3H / 32, EMB / 32), dim3(32, 8), 0, stream,
                       W, Wt);
    hipLaunchKernelGGL(gemm128, dim3(4096 + 8), dim3(256), 0, stream,
                       xb, Wt, bias, zb, fb, ob);
    hipLaunchKernelGGL(fo_pool, dim3(B_DIM * HID / 2 / 256), dim3(256), 0, stream,
                       (const unsigned*)zb, (const unsigned*)fb,
                       (const unsigned*)ob, hb);
    hipLaunchKernelGGL(classify, dim3(B_DIM), dim3(64), 0, stream,
                       hb, Wout, bout, out);
}